// Round 18
// baseline (804.728 us; speedup 1.0000x reference)
//
#include <hip/hip_runtime.h>

// PathDecoder: B=256, L=192, H=320, E=128, V=27000, T=8
constexpr int Bn = 256;
constexpr int Ln = 192;
constexpr int Hn = 320;
constexpr int En = 128;
constexpr int Vn = 27000;
constexpr int Tn = 8;
constexpr float NEGV   = -1e9f;
constexpr float LN_EPS = 1e-5f;

typedef __attribute__((ext_vector_type(8))) short bf16x8;
typedef __attribute__((ext_vector_type(4))) float f32x4;
typedef unsigned long long u64;
typedef unsigned short u16;

__device__ __forceinline__ float sigmoidf_(float x) { return 1.f / (1.f + expf(-x)); }
__device__ __forceinline__ u16 f2bf(float x) {
  unsigned u = __float_as_uint(x);
  return (u16)((u + 0x7fffu + ((u >> 16) & 1u)) >> 16);
}
__device__ __forceinline__ float bf2f(u16 h) { return __uint_as_float((unsigned)h << 16); }
__device__ __forceinline__ unsigned mono(float f) {
  unsigned u = __float_as_uint(f);
  return (u & 0x80000000u) ? ~u : (u | 0x80000000u);
}
__device__ __forceinline__ u64 shfl_xor_u64(u64 x, int off) {
  unsigned lo = (unsigned)x, hi = (unsigned)(x >> 32);
  lo = __shfl_xor(lo, off, 64);
  hi = __shfl_xor(hi, off, 64);
  return ((u64)hi << 32) | lo;
}

// ---------------------------------------------------------------------------
// ONE prep kernel: weight splits/transposes + bias + h0/c0 + amax zero.
// grid 1280 x 320 (5 waves).
__global__ __launch_bounds__(320) void k_prep(
    const float* __restrict__ enc, const int* __restrict__ lens,
    const float* __restrict__ emb, const float* __restrict__ proj_w,
    const float* __restrict__ w_ih, const float* __restrict__ w_hh,
    const float* __restrict__ b_ih, const float* __restrict__ b_hh,
    const float* __restrict__ attn_w, const float* __restrict__ concat_w,
    u16* __restrict__ pwh, u16* __restrict__ pwl,
    u16* __restrict__ ebh, u16* __restrict__ ebl,
    u16* __restrict__ wch, u16* __restrict__ wcl,
    float* __restrict__ awT, float* __restrict__ cwT, float* __restrict__ biasc,
    float* __restrict__ h32, float* __restrict__ c32,
    u16* __restrict__ hh, u16* __restrict__ hl, u64* __restrict__ amax) {
  const int gid = blockIdx.x * 320 + threadIdx.x;
  const int NT = gridDim.x * 320;

  // h0 = c0 = mean over valid length (first 256 blocks, one row each)
  if (blockIdx.x < Bn) {
    int b = blockIdx.x, t = threadIdx.x;
    const float* p = enc + (size_t)b * Ln * Hn + t;
    float s = 0.f;
#pragma unroll 8
    for (int l = 0; l < Ln; ++l) s += p[(size_t)l * Hn];
    float hv = s / (float)lens[b];
    size_t o = (size_t)b * Hn + t;
    h32[o] = hv; c32[o] = hv;
    u16 hb = f2bf(hv);
    hh[o] = hb; hl[o] = f2bf(hv - bf2f(hb));
  }

  for (int i = gid; i < Vn * Hn / 4; i += NT) {
    float4 v = ((const float4*)proj_w)[i];
    u16 h0 = f2bf(v.x), h1 = f2bf(v.y), h2 = f2bf(v.z), h3 = f2bf(v.w);
    ((ushort4*)pwh)[i] = make_ushort4(h0, h1, h2, h3);
    ((ushort4*)pwl)[i] = make_ushort4(f2bf(v.x - bf2f(h0)), f2bf(v.y - bf2f(h1)),
                                      f2bf(v.z - bf2f(h2)), f2bf(v.w - bf2f(h3)));
  }
  for (int i = gid; i < Vn * En / 4; i += NT) {
    float4 v = ((const float4*)emb)[i];
    u16 h0 = f2bf(v.x), h1 = f2bf(v.y), h2 = f2bf(v.z), h3 = f2bf(v.w);
    ((ushort4*)ebh)[i] = make_ushort4(h0, h1, h2, h3);
    ((ushort4*)ebl)[i] = make_ushort4(f2bf(v.x - bf2f(h0)), f2bf(v.y - bf2f(h1)),
                                      f2bf(v.z - bf2f(h2)), f2bf(v.w - bf2f(h3)));
  }
  for (int i = gid; i < 4 * Hn * 112; i += NT) {   // w_cat [1280][448] split
    int r = i / 112, k = (i % 112) * 4;
    const float* src = (k < En) ? (w_ih + (size_t)r * En + k)
                                : (w_hh + (size_t)r * Hn + (k - En));
    float4 v = *(const float4*)src;
    size_t o = (size_t)r * 448 + k;
    u16 h0 = f2bf(v.x), h1 = f2bf(v.y), h2 = f2bf(v.z), h3 = f2bf(v.w);
    *(ushort4*)(wch + o) = make_ushort4(h0, h1, h2, h3);
    *(ushort4*)(wcl + o) = make_ushort4(f2bf(v.x - bf2f(h0)), f2bf(v.y - bf2f(h1)),
                                        f2bf(v.z - bf2f(h2)), f2bf(v.w - bf2f(h3)));
  }
  for (int i = gid; i < Hn * Hn; i += NT) {        // awT[k][j] = attn_w[j][k]
    int k = i / Hn, j = i % Hn;
    awT[i] = attn_w[(size_t)j * Hn + k];
  }
  for (int i = gid; i < 2 * Hn * Hn; i += NT) {    // cwT[k][j] = concat_w[j][k]
    int k = i / Hn, j = i % Hn;
    cwT[i] = concat_w[(size_t)j * (2 * Hn) + k];
  }
  for (int i = gid; i < 4 * Hn; i += NT) biasc[i] = b_ih[i] + b_hh[i];
  for (int i = gid; i < Tn * Bn; i += NT) amax[i] = 0ull;
}

// ---------------------------------------------------------------------------
// gates GEMM (split-bf16 MFMA) + LSTM cell.
// grid 80 = (20 j-blocks) x (4 b-quarters); block 256 (4 waves).
__global__ __launch_bounds__(256) void k_gates(
    const u16* __restrict__ ebh, const u16* __restrict__ ebl,
    const u64* __restrict__ amax_prev, int t,
    const u16* __restrict__ wch, const u16* __restrict__ wcl,
    const float* __restrict__ biasc,
    const u16* __restrict__ hh_in, const u16* __restrict__ hl_in,
    const float* __restrict__ c_in, float* __restrict__ c_out,
    float* __restrict__ h32, u16* __restrict__ hh_out, u16* __restrict__ hl_out) {
  int tid = threadIdx.x, wv = tid >> 6, lane = tid & 63;
  int j0 = (blockIdx.x >> 2) * 16;
  int b0 = (blockIdx.x & 3) * 64 + wv * 16;
  int lr = lane & 15, hi4 = lane >> 4, kg = hi4 * 8;
  int r = b0 + lr;
  int tkr = (t == 0) ? 1 : (int)(~(unsigned)amax_prev[r]);

  f32x4 acc[4];
#pragma unroll
  for (int j = 0; j < 4; ++j) acc[j] = (f32x4){0.f, 0.f, 0.f, 0.f};
  for (int k0 = 0; k0 < 448; k0 += 32) {
    bf16x8 af[2], bw[4][2];
    if (k0 < En) {
      size_t o = (size_t)tkr * En + k0 + kg;
      af[0] = *(const bf16x8*)(ebh + o);
      af[1] = *(const bf16x8*)(ebl + o);
    } else {
      size_t o = (size_t)r * Hn + (k0 - En) + kg;
      af[0] = *(const bf16x8*)(hh_in + o);
      af[1] = *(const bf16x8*)(hl_in + o);
    }
#pragma unroll
    for (int g = 0; g < 4; ++g) {
      size_t o = (size_t)(g * Hn + j0 + lr) * 448 + k0 + kg;
      bw[g][0] = *(const bf16x8*)(wch + o);
      bw[g][1] = *(const bf16x8*)(wcl + o);
    }
#pragma unroll
    for (int g = 0; g < 4; ++g) {
      acc[g] = __builtin_amdgcn_mfma_f32_16x16x32_bf16(af[0], bw[g][0], acc[g], 0, 0, 0);
      acc[g] = __builtin_amdgcn_mfma_f32_16x16x32_bf16(af[0], bw[g][1], acc[g], 0, 0, 0);
      acc[g] = __builtin_amdgcn_mfma_f32_16x16x32_bf16(af[1], bw[g][0], acc[g], 0, 0, 0);
    }
  }
  int jc = j0 + lr;
#pragma unroll
  for (int j = 0; j < 4; ++j) {
    int b = b0 + hi4 * 4 + j;
    float iv = acc[0][j] + biasc[jc];
    float fv = acc[1][j] + biasc[Hn + jc];
    float gv = acc[2][j] + biasc[2 * Hn + jc];
    float ov = acc[3][j] + biasc[3 * Hn + jc];
    float co = c_in[(size_t)b * Hn + jc];
    float cn = sigmoidf_(fv) * co + sigmoidf_(iv) * tanhf(gv);
    float hn = sigmoidf_(ov) * tanhf(cn);
    size_t o = (size_t)b * Hn + jc;
    c_out[o] = cn;
    h32[o] = hn;
    u16 hb = f2bf(hn);
    hh_out[o] = hb;
    hl_out[o] = f2bf(hn - bf2f(hb));
  }
}

// ---------------------------------------------------------------------------
// attention (wave-split matvecs + online softmax, fp32 enc) + cat + LN.
// one block per batch row; 512 threads (8 waves).
__global__ __launch_bounds__(512) void k_attn(
    const float* __restrict__ enc, const int* __restrict__ lens,
    const float* __restrict__ awT, const float* __restrict__ cwT,
    const float* __restrict__ gamma, const float* __restrict__ beta,
    const float* __restrict__ h32, u16* __restrict__ th, u16* __restrict__ tl) {
  __shared__ float eL[64 * Hn];     // 80 KB enc chunk
  __shared__ float xs[2 * Hn];      // [h | ctx]
  __shared__ float ahs[Hn];
  __shared__ float part[8][Hn];
  __shared__ float sc[64];
  __shared__ float rmS, rsS, rfS, rmu, rvar;

  int b = blockIdx.x, tid = threadIdx.x, wv = tid >> 6, lane = tid & 63;
  if (tid < Hn) xs[tid] = h32[(size_t)b * Hn + tid];
  if (tid == 0) { rmS = -3.402823466e38f; rsS = 0.f; }
  __syncthreads();

  // ah = attn_w @ h : wave-split over k
  {
    float a[5] = {0.f, 0.f, 0.f, 0.f, 0.f};
    int kbeg = wv * 40;
    for (int k = kbeg; k < kbeg + 40; ++k) {
      float hk = xs[k];
      const float* row = awT + (size_t)k * Hn;
#pragma unroll
      for (int q = 0; q < 5; ++q) a[q] = fmaf(row[lane + 64 * q], hk, a[q]);
    }
#pragma unroll
    for (int q = 0; q < 5; ++q) part[wv][lane + 64 * q] = a[q];
  }
  __syncthreads();
  if (tid < Hn) {
    float s = 0.f;
#pragma unroll
    for (int w = 0; w < 8; ++w) s += part[w][tid];
    ahs[tid] = s;
  }
  __syncthreads();

  // online-softmax attention, single enc pass (3 chunks of 64 rows)
  int len = lens[b];
  float ctxacc = 0.f;
  const float* encB = enc + (size_t)b * Ln * Hn;
  for (int c = 0; c < 3; ++c) {
    const float4* src = (const float4*)(encB + (size_t)c * 64 * Hn);
#pragma unroll
    for (int i = 0; i < 10; ++i) ((float4*)eL)[tid + i * 512] = src[tid + i * 512];
    __syncthreads();
#pragma unroll
    for (int r = 0; r < 8; ++r) {
      int l = wv * 8 + r;
      float s = 0.f;
#pragma unroll
      for (int c5 = 0; c5 < 5; ++c5)
        s += eL[l * Hn + lane + 64 * c5] * ahs[lane + 64 * c5];
#pragma unroll
      for (int off = 32; off > 0; off >>= 1) s += __shfl_xor(s, off, 64);
      if (lane == 0) sc[l] = s + ((c * 64 + l < len) ? 0.f : NEGV);
    }
    __syncthreads();
    if (wv == 0) {
      float v = sc[lane];
      float m = v;
#pragma unroll
      for (int off = 32; off > 0; off >>= 1) m = fmaxf(m, __shfl_xor(m, off, 64));
      float oldm = rmS;
      float newm = fmaxf(oldm, m);
      float p = expf(v - newm);
      sc[lane] = p;
      float s = p;
#pragma unroll
      for (int off = 32; off > 0; off >>= 1) s += __shfl_xor(s, off, 64);
      if (lane == 0) {
        rfS = expf(oldm - newm);
        rsS = rsS * rfS + s;
        rmS = newm;
      }
    }
    __syncthreads();
    if (tid < Hn) {
      float f = rfS;
      float a = 0.f;
#pragma unroll 8
      for (int l = 0; l < 64; ++l) a += sc[l] * eL[l * Hn + tid];
      ctxacc = ctxacc * f + a;
    }
    __syncthreads();
  }
  if (tid < Hn) xs[Hn + tid] = ctxacc / rsS;
  __syncthreads();

  // cat = [h|ctx] @ concat_w^T : wave-split over 640 k
  {
    float a[5] = {0.f, 0.f, 0.f, 0.f, 0.f};
    int kbeg = wv * 80;
    for (int k = kbeg; k < kbeg + 80; ++k) {
      float xk = xs[k];
      const float* row = cwT + (size_t)k * Hn;
#pragma unroll
      for (int q = 0; q < 5; ++q) a[q] = fmaf(row[lane + 64 * q], xk, a[q]);
    }
#pragma unroll
    for (int q = 0; q < 5; ++q) part[wv][lane + 64 * q] = a[q];
  }
  __syncthreads();
  float catv = 0.f;
  if (tid < Hn) {
    float s = 0.f;
#pragma unroll
    for (int w = 0; w < 8; ++w) s += part[w][tid];
    catv = s;
    ahs[tid] = s;
  }
  __syncthreads();
  if (tid < 64) {
    float s1 = 0.f, s2 = 0.f;
    for (int i = tid; i < Hn; i += 64) { float v = ahs[i]; s1 += v; s2 += v * v; }
#pragma unroll
    for (int off = 32; off > 0; off >>= 1) {
      s1 += __shfl_xor(s1, off, 64);
      s2 += __shfl_xor(s2, off, 64);
    }
    if (tid == 0) {
      float mu = s1 * (1.f / 320.f);
      rmu = mu;
      rvar = s2 * (1.f / 320.f) - mu * mu;
    }
  }
  __syncthreads();
  if (tid < Hn) {
    float rstd = 1.f / sqrtf(rvar + LN_EPS);
    float y = (catv - rmu) * rstd * gamma[tid] + beta[tid];
    float tv = tanhf(y);
    u16 tb = f2bf(tv);
    size_t o = (size_t)b * Hn + tid;
    th[o] = tb;
    tl[o] = f2bf(tv - bf2f(tb));
  }
}

// ---------------------------------------------------------------------------
// projection (split-bf16 MFMA) + fused argmax + LDS-coalesced logits write.
// grid 424 (= 8 XCD x 53 pairs), block 256 (4 waves).
__global__ __launch_bounds__(256) void k_proj(
    const u16* __restrict__ th, const u16* __restrict__ tl,
    const u16* __restrict__ pwh, const u16* __restrict__ pwl,
    float* __restrict__ ot, u64* __restrict__ amax_t) {
  __shared__ u64 red[4][64];
  __shared__ float sL[64][260];      // 64 rows x 256 cols, stride 260 (16B-aligned)
  int tid = threadIdx.x, wave = tid >> 6, lane = tid & 63;
  int bid = blockIdx.x;               // 0..423
  int xcd = bid & 7, s = bid >> 3;    // s 0..52
  int g = xcd * 53 + s;               // bijective 0..423
  int vblk = g >> 2, y = g & 3;
  int v0 = vblk * 256 + wave * 64;
  int b0 = y * 64;
  int lr = lane & 15, hi4 = lane >> 4, kg = hi4 * 8;

  f32x4 acc[4][4];
#pragma unroll
  for (int i = 0; i < 4; ++i)
#pragma unroll
    for (int j = 0; j < 4; ++j) acc[i][j] = (f32x4){0.f, 0.f, 0.f, 0.f};
  const bf16x8 zf = {0, 0, 0, 0, 0, 0, 0, 0};

  for (int k0 = 0; k0 < Hn; k0 += 32) {
    bf16x8 af[4][2], bw[4][2];
#pragma unroll
    for (int mt = 0; mt < 4; ++mt) {
      size_t o = (size_t)(b0 + mt * 16 + lr) * Hn + k0 + kg;
      af[mt][0] = *(const bf16x8*)(th + o);
      af[mt][1] = *(const bf16x8*)(tl + o);
    }
#pragma unroll
    for (int nt = 0; nt < 4; ++nt) {
      int v = v0 + nt * 16 + lr;
      if (v < Vn) {
        size_t o = (size_t)v * Hn + k0 + kg;
        bw[nt][0] = *(const bf16x8*)(pwh + o);
        bw[nt][1] = *(const bf16x8*)(pwl + o);
      } else {
        bw[nt][0] = zf; bw[nt][1] = zf;
      }
    }
#pragma unroll
    for (int mt = 0; mt < 4; ++mt)
#pragma unroll
      for (int nt = 0; nt < 4; ++nt) {
        acc[mt][nt] = __builtin_amdgcn_mfma_f32_16x16x32_bf16(af[mt][0], bw[nt][0], acc[mt][nt], 0, 0, 0);
        acc[mt][nt] = __builtin_amdgcn_mfma_f32_16x16x32_bf16(af[mt][0], bw[nt][1], acc[mt][nt], 0, 0, 0);
        acc[mt][nt] = __builtin_amdgcn_mfma_f32_16x16x32_bf16(af[mt][1], bw[nt][0], acc[mt][nt], 0, 0, 0);
      }
  }

  int orow = hi4 * 4;
  // stage accumulators into LDS tile [row][col]
#pragma unroll
  for (int mt = 0; mt < 4; ++mt)
#pragma unroll
    for (int nt = 0; nt < 4; ++nt)
#pragma unroll
      for (int j = 0; j < 4; ++j)
        sL[mt * 16 + orow + j][wave * 64 + nt * 16 + lr] = acc[mt][nt][j];

  // fused argmax: key = (mono(val)<<32) | ~idx ; max key == first max
  u64 best[4][4];
#pragma unroll
  for (int mt = 0; mt < 4; ++mt)
#pragma unroll
    for (int j = 0; j < 4; ++j) {
      u64 k = 0ull;
#pragma unroll
      for (int nt = 0; nt < 4; ++nt) {
        int v = v0 + nt * 16 + lr;
        if (v < Vn) {
          u64 kk = ((u64)mono(acc[mt][nt][j]) << 32) | (u64)(unsigned)(~v);
          if (kk > k) k = kk;
        }
      }
      best[mt][j] = k;
    }
#pragma unroll
  for (int off = 1; off < 16; off <<= 1)
#pragma unroll
    for (int mt = 0; mt < 4; ++mt)
#pragma unroll
      for (int j = 0; j < 4; ++j) {
        u64 o = shfl_xor_u64(best[mt][j], off);
        if (o > best[mt][j]) best[mt][j] = o;
      }
  if (lr == 0) {
#pragma unroll
    for (int mt = 0; mt < 4; ++mt)
#pragma unroll
      for (int j = 0; j < 4; ++j) red[wave][mt * 16 + orow + j] = best[mt][j];
  }
  __syncthreads();
  if (tid < 64) {
    u64 k = red[0][tid];
#pragma unroll
    for (int w = 1; w < 4; ++w)
      if (red[w][tid] > k) k = red[w][tid];
    atomicMax(&amax_t[b0 + tid], k);
  }

  // coalesced logits write: each row is 1 KB contiguous (64 threads x f32x4)
  int rem = Vn - vblk * 256;               // valid cols this v-panel (<=256)
  int colq = tid & 63, r0 = tid >> 6;
  if (colq * 4 < rem) {
#pragma unroll
    for (int r = r0; r < 64; r += 4) {
      f32x4 vv = *(const f32x4*)&sL[r][colq * 4];
      __builtin_nontemporal_store(vv,
          (f32x4*)(ot + (size_t)(b0 + r) * Vn + vblk * 256 + colq * 4));
    }
  }
}

// ---------------------------------------------------------------------------
extern "C" void kernel_launch(void* const* d_in, const int* in_sizes, int n_in,
                              void* d_out, int out_size, void* d_ws, size_t ws_size,
                              hipStream_t stream) {
  const float* enc      = (const float*)d_in[0];
  const int*   lens     = (const int*)d_in[1];
  const float* emb      = (const float*)d_in[2];
  const float* w_ih     = (const float*)d_in[3];
  const float* w_hh     = (const float*)d_in[4];
  const float* b_ih     = (const float*)d_in[5];
  const float* b_hh     = (const float*)d_in[6];
  const float* attn_w   = (const float*)d_in[7];
  const float* concat_w = (const float*)d_in[8];
  const float* gamma    = (const float*)d_in[9];
  const float* beta     = (const float*)d_in[10];
  const float* proj_w   = (const float*)d_in[11];
  float* out = (float*)d_out;

  char* p = (char*)d_ws;
  auto alloc = [&](size_t bytes, size_t align) -> char* {
    uintptr_t a = ((uintptr_t)p + align - 1) & ~(uintptr_t)(align - 1);
    char* r = (char*)a;
    p = r + bytes;
    return r;
  };
  const size_t HB = (size_t)Bn * Hn;
  u64* amax  = (u64*)alloc((size_t)Tn * Bn * 8, 8);
  float* h32 = (float*)alloc(HB * 4, 16);
  float* c32 = (float*)alloc(2 * HB * 4, 16);
  float* awT = (float*)alloc((size_t)Hn * Hn * 4, 16);
  float* cwT = (float*)alloc((size_t)2 * Hn * Hn * 4, 16);
  float* biasc = (float*)alloc((size_t)4 * Hn * 4, 16);
  u16* hh  = (u16*)alloc(2 * HB * 2, 16);
  u16* hl  = (u16*)alloc(2 * HB * 2, 16);
  u16* th  = (u16*)alloc(HB * 2, 16);
  u16* tl  = (u16*)alloc(HB * 2, 16);
  u16* wch = (u16*)alloc((size_t)4 * Hn * 448 * 2, 16);
  u16* wcl = (u16*)alloc((size_t)4 * Hn * 448 * 2, 16);
  u16* ebh = (u16*)alloc((size_t)Vn * En * 2, 16);
  u16* ebl = (u16*)alloc((size_t)Vn * En * 2, 16);
  u16* pwh = (u16*)alloc((size_t)Vn * Hn * 2, 16);
  u16* pwl = (u16*)alloc((size_t)Vn * Hn * 2, 16);

  k_prep<<<1280, 320, 0, stream>>>(enc, lens, emb, proj_w, w_ih, w_hh, b_ih, b_hh,
                                   attn_w, concat_w, pwh, pwl, ebh, ebl, wch, wcl,
                                   awT, cwT, biasc, h32, c32, hh, hl, amax);

  for (int t = 0; t < Tn; ++t) {
    int hin = t & 1, hout = hin ^ 1;
    const u64* aprev = amax + (size_t)((t == 0) ? 0 : (t - 1)) * Bn;
    k_gates<<<80, 256, 0, stream>>>(ebh, ebl, aprev, t, wch, wcl, biasc,
                                    hh + hin * HB, hl + hin * HB,
                                    c32 + hin * HB, c32 + hout * HB,
                                    h32, hh + hout * HB, hl + hout * HB);
    k_attn<<<Bn, 512, 0, stream>>>(enc, lens, awT, cwT, gamma, beta, h32, th, tl);
    k_proj<<<424, 256, 0, stream>>>(th, tl, pwh, pwl,
                                    out + (size_t)t * Bn * Vn,
                                    amax + (size_t)t * Bn);
  }
}